// Round 9
// baseline (491.761 us; speedup 1.0000x reference)
//
#include <hip/hip_runtime.h>
#include <hip/hip_bf16.h>
#include <math.h>

#define NB 32
#define NQ 2048
#define NK 512
#define NE 16
#define NH 32
#define NL 20
#define NHID 50
#define NO 41

// ws layout (floats):
// gi   : [64][512][96] @ 0        (3,145,728)  OVERLAID with att (gru before attn)
// att  : [65536][64]   @ 0        (4,194,304)  normalized P@val (pre-Wv)
// val  : [32][512][64] @ 4194304  (1,048,576)
// ktab : [512][16]     @ 5242880  (8,192)
// w1p  : [50][64]      @ 5251072  (3,200)      W1 @ Wv
// b1p  : [50]          @ 5254272  (64)         b1 + W1 @ bv
// total ~21.0 MB (proven size)

__device__ __forceinline__ float fsigmoid(float x) {
  return __builtin_amdgcn_rcpf(1.0f + __expf(-x));
}
__device__ __forceinline__ float ftanh(float x) {
  return 1.0f - 2.0f * __builtin_amdgcn_rcpf(__expf(2.0f * x) + 1.0f);
}
__device__ __forceinline__ float bperm(int lane, float v) {
  return __builtin_bit_cast(
      float, __builtin_amdgcn_ds_bpermute(lane << 2, __builtin_bit_cast(int, v)));
}

// blocks 0-1: k-table. block 2: fold Wv into W1.
__global__ __launch_bounds__(256) void prep_kernel(
    const float* __restrict__ refq, const float* __restrict__ Wk,
    const float* __restrict__ bk,
    const float* __restrict__ Wv, const float* __restrict__ bv,
    const float* __restrict__ W1, const float* __restrict__ b1,
    float* __restrict__ ktab, float* __restrict__ w1p,
    float* __restrict__ b1p) {
  const int tid = threadIdx.x;
  if (blockIdx.x < 2) {
    const int r = blockIdx.x * 256 + tid;
    const float divs[8] = {1.0f, 0.74989421f, 0.56234133f, 0.42169650f,
                           0.31622777f, 0.23713737f, 0.17782794f, 0.13335214f};
    float pos = refq[r];
    float emb[NE];
#pragma unroll
    for (int m = 0; m < 8; ++m) {
      float a = 48.0f * pos * divs[m];
      emb[2 * m] = sinf(a);
      emb[2 * m + 1] = cosf(a);
    }
#pragma unroll
    for (int e = 0; e < NE; ++e) {
      float acc = bk[e];
#pragma unroll
      for (int i = 0; i < NE; ++i) acc += emb[i] * Wk[e * NE + i];
      ktab[r * NE + e] = acc;
    }
  } else {
    for (int e = tid; e < NHID * 64; e += 256) {
      const int o = e >> 6, i = e & 63;
      float acc = 0.f;
#pragma unroll 4
      for (int d = 0; d < 64; ++d) acc += W1[o * 64 + d] * Wv[d * 64 + i];
      w1p[e] = acc;
    }
    if (tid < NHID) {
      float acc = b1[tid];
#pragma unroll 4
      for (int d = 0; d < 64; ++d) acc += W1[tid * 64 + d] * bv[d];
      b1p[tid] = acc;
    }
  }
}

// Input-side gates, fully parallel: gi[c][t][g] = z[b][t] . Wih[g] + bih[g]
// (+ bhh[g] folded for the r,z gates; n keeps bhh separate since it's scaled
// by the reset gate).
__global__ __launch_bounds__(256) void prep_gi_kernel(
    const float* __restrict__ z,
    const float* __restrict__ Wih_f, const float* __restrict__ bih_f,
    const float* __restrict__ bhh_f,
    const float* __restrict__ Wih_b, const float* __restrict__ bih_b,
    const float* __restrict__ bhh_b, float* __restrict__ gi) {
  const int row = blockIdx.x * 256 + threadIdx.x;  // chain*512 + t
  const int c = row >> 9, t = row & 511;
  const int dir = c >> 5, b = c & 31;
  const float* __restrict__ Wih = dir ? Wih_b : Wih_f;
  const float* __restrict__ bih = dir ? bih_b : bih_f;
  const float* __restrict__ bhh = dir ? bhh_b : bhh_f;
  const float* __restrict__ zr = z + ((size_t)b * NK + t) * NL;
  float x[NL];
#pragma unroll
  for (int i = 0; i < NL; ++i) x[i] = zr[i];
  float* __restrict__ go = gi + (size_t)row * 96;
  for (int g = 0; g < 96; ++g) {
    float acc = bih[g] + (g < 64 ? bhh[g] : 0.f);
#pragma unroll
    for (int i = 0; i < NL; ++i) acc += x[i] * Wih[g * NL + i];
    go[g] = acc;
  }
}

// Serial GRU, minimal critical path: per step only {16 independent shfl
// h-gather, 48 FMA, 3 shfl_xor, activations}. Input gates come precomputed
// from gi via 4-deep GLOBAL prefetch (vmcnt queue, not the DS queue).
__global__ __launch_bounds__(64) void gru_kernel(
    const float* __restrict__ gi,
    const float* __restrict__ Whh_f, const float* __restrict__ bhh_f,
    const float* __restrict__ Whh_b, const float* __restrict__ bhh_b,
    float* __restrict__ val) {
  const int c = blockIdx.x;
  const int dir = c >> 5, b = c & 31;
  const int l = threadIdx.x;
  const int j = l & 31, half = l >> 5;
  const int hbase = half * 16;
  const float* __restrict__ Whh = dir ? Whh_b : Whh_f;
  const float* __restrict__ bhh = dir ? bhh_b : bhh_f;

  float wr[16], wz[16], wn[16];
#pragma unroll
  for (int i = 0; i < 16; ++i) {
    wr[i] = Whh[j * 32 + hbase + i];
    wz[i] = Whh[(j + 32) * 32 + hbase + i];
    wn[i] = Whh[(j + 64) * 32 + hbase + i];
  }
  const float bhn = bhh[j + 64];
  float h = 0.f;
  const float* __restrict__ gic = gi + (size_t)c * NK * 96;

  float r0, z0, n0, r1, z1, n1, r2, z2, n2, r3, z3, n3;
  auto giload = [&](int s, float& gr, float& gz, float& gn) {
    const int tt = dir ? (NK - 1 - s) : s;
    gr = gic[tt * 96 + j];
    gz = gic[tt * 96 + 32 + j];
    gn = gic[tt * 96 + 64 + j];
  };
  giload(0, r0, z0, n0);
  giload(1, r1, z1, n1);
  giload(2, r2, z2, n2);
  giload(3, r3, z3, n3);

  auto step = [&](int s, float& gr, float& gz, float& gn) {
    const float gir = gr, giz = gz, gin = gn;
    if (s + 4 < NK) giload(s + 4, gr, gz, gn);  // global prefetch (vmcnt)
    float hv[16];
#pragma unroll
    for (int t = 0; t < 16; ++t) hv[t] = __shfl(h, hbase + t);  // independent
    float pr0 = 0.f, pr1 = 0.f, pz0 = 0.f, pz1 = 0.f, pn0 = 0.f, pn1 = 0.f;
#pragma unroll
    for (int t = 0; t < 8; ++t) {
      pr0 += wr[t] * hv[t];
      pz0 += wz[t] * hv[t];
      pn0 += wn[t] * hv[t];
      pr1 += wr[8 + t] * hv[8 + t];
      pz1 += wz[8 + t] * hv[8 + t];
      pn1 += wn[8 + t] * hv[8 + t];
    }
    const float cr = pr0 + pr1;
    const float cz = pz0 + pz1;
    const float cn = pn0 + pn1;
    const float sr = cr + __shfl_xor(cr, 32);
    const float sz = cz + __shfl_xor(cz, 32);
    const float snh = cn + __shfl_xor(cn, 32);
    const float rg = fsigmoid(gir + sr);             // bih+bhh folded in gi
    const float ug = fsigmoid(giz + sz);
    const float ng = ftanh(gin + rg * (snh + bhn));  // bih_n in gi; bhn here
    h = ng + ug * (h - ng);
    if (half == 0) {
      const int tt = dir ? (NK - 1 - s) : s;
      val[((size_t)b * NK + tt) * 64 + dir * 32 + j] = h;
    }
  };
  for (int s = 0; s < NK; s += 4) {
    step(s, r0, z0, n0);
    step(s + 1, r1, z1, n1);
    step(s + 2, r2, z2, n2);
    step(s + 3, r3, z3, n3);
  }
}

// R=8 register-reuse attention. Wave = 8 groups x 8 lanes; group owns 8 rows.
// Lane (g, r8) scores ONLY row rowbase+g*8+r8 (zero redundancy), shares the
// 8 p's via bpermute, accumulates acc[8][8] (row m, dims r8*8..+8) — every
// loaded v float serves 8 rows. k-stagger (group g at k-block (g+kb)&7) makes
// all 64 lanes read distinct v bytes; skewed kt LDS keeps groups conflict-free.
__global__ __launch_bounds__(256) void attn_core_kernel(
    const float* __restrict__ tsteps, const float* __restrict__ ktab,
    const float* __restrict__ val,
    const float* __restrict__ Wq, const float* __restrict__ bq,
    float* __restrict__ att) {
  __shared__ __align__(16) float kts[NK * NE + 32];  // skewed, 33 KB
  __shared__ float wqs[NE * NE];
  __shared__ float bqs[NE];
  const int tid = threadIdx.x;
  for (int i = tid; i < NK * NE; i += 256) {
    const int k = i >> 4, e = i & 15;
    kts[(k << 4) + ((k >> 6) << 2) + e] = ktab[i];
  }
  for (int i = tid; i < NE * NE; i += 256) wqs[i] = Wq[i];
  if (tid < NE) bqs[tid] = bq[tid];
  __syncthreads();

  const int lane = tid & 63;
  const int g = lane >> 3;      // group 0..7
  const int r8 = lane & 7;      // row-in-group for scoring; d-eighth for acc
  const int wave = tid >> 6;
  const int rowbase = blockIdx.x * 256 + wave * 64 + g * 8;
  const int myrow = rowbase + r8;
  const int b = myrow >> 11;    // uniform per wave (64-row span, 64|2048)

  const float pos = tsteps[myrow];
  const float divs[8] = {1.0f, 0.74989421f, 0.56234133f, 0.42169650f,
                         0.31622777f, 0.23713737f, 0.17782794f, 0.13335214f};
  float emb[NE];
#pragma unroll
  for (int m = 0; m < 8; ++m) {
    float a = 48.0f * pos * divs[m];
    emb[2 * m] = sinf(a);
    emb[2 * m + 1] = cosf(a);
  }
  float q[NE];
#pragma unroll
  for (int e = 0; e < NE; ++e) {
    float acc = bqs[e];
#pragma unroll
    for (int i = 0; i < NE; ++i) acc += emb[i] * wqs[e * NE + i];
    q[e] = acc * 0.25f;  // fold 1/sqrt(E)
  }
  const int lb = lane & ~7;  // group's lane 0
  const float* __restrict__ vb = val + (size_t)b * NK * 64;

  float acc[8][8];
#pragma unroll
  for (int m = 0; m < 8; ++m)
#pragma unroll
    for (int d = 0; d < 8; ++d) acc[m][d] = 0.f;
  float lsum = 0.f;

  for (int kb = 0; kb < 8; ++kb) {
    const int khi = (g + kb) & 7;
    const float* __restrict__ kbase = &kts[(khi << 10) + (khi << 2)];
    const float* __restrict__ vkb = vb + (size_t)(khi << 6) * 64 + r8 * 8;
#pragma unroll 2
    for (int i = 0; i < 64; ++i) {
      const float4* kr = (const float4*)(kbase + i * 16);  // group-broadcast
      const float4 k0 = kr[0], k1 = kr[1], k2 = kr[2], k3 = kr[3];
      float s;
      s  = q[0] * k0.x + q[1] * k0.y + q[2] * k0.z + q[3] * k0.w;
      s += q[4] * k1.x + q[5] * k1.y + q[6] * k1.z + q[7] * k1.w;
      s += q[8] * k2.x + q[9] * k2.y + q[10] * k2.z + q[11] * k2.w;
      s += q[12] * k3.x + q[13] * k3.y + q[14] * k3.z + q[15] * k3.w;
      const float p = __expf(s);  // scores O(1): no max-sub needed
      lsum += p;
      const float* vr = vkb + i * 64;
      const float4 va = *(const float4*)(vr);
      const float4 vb4 = *(const float4*)(vr + 4);
      float pm[8];
#pragma unroll
      for (int m = 0; m < 8; ++m) pm[m] = bperm(lb + m, p);
#pragma unroll
      for (int m = 0; m < 8; ++m) {
        acc[m][0] += pm[m] * va.x;  acc[m][1] += pm[m] * va.y;
        acc[m][2] += pm[m] * va.z;  acc[m][3] += pm[m] * va.w;
        acc[m][4] += pm[m] * vb4.x; acc[m][5] += pm[m] * vb4.y;
        acc[m][6] += pm[m] * vb4.z; acc[m][7] += pm[m] * vb4.w;
      }
    }
  }
  float* ob = att + (size_t)rowbase * 64 + r8 * 8;
#pragma unroll
  for (int m = 0; m < 8; ++m) {
    const float im = 1.0f / bperm(lb + m, lsum);
    float4 o;
    o.x = acc[m][0] * im; o.y = acc[m][1] * im;
    o.z = acc[m][2] * im; o.w = acc[m][3] * im;
    *(float4*)(ob + m * 64) = o;
    o.x = acc[m][4] * im; o.y = acc[m][5] * im;
    o.z = acc[m][6] * im; o.w = acc[m][7] * im;
    *(float4*)(ob + m * 64 + 4) = o;
  }
}

// Per-row MLP on folded weights: out = W2 @ relu(W1' @ ar + b1') + b2.
__global__ __launch_bounds__(256) void mlp_kernel(
    const float* __restrict__ att,
    const float* __restrict__ w1p, const float* __restrict__ b1p,
    const float* __restrict__ W2, const float* __restrict__ b2,
    float* __restrict__ out) {
  __shared__ __align__(16) float w1s[NHID * 64];   // 12.8 KB
  __shared__ __align__(16) float w2s[NO * NHID];   // 8.2 KB
  __shared__ float b1s[NHID], b2s[NO];
  const int tid = threadIdx.x;
  for (int i = tid; i < NHID * 64; i += 256) w1s[i] = w1p[i];
  for (int i = tid; i < NO * NHID; i += 256) w2s[i] = W2[i];
  if (tid < NHID) b1s[tid] = b1p[tid];
  if (tid < NO) b2s[tid] = b2[tid];
  __syncthreads();

  const int row = blockIdx.x * 256 + tid;
  float ar[64];
  const float4* a4 = (const float4*)(att + (size_t)row * 64);
#pragma unroll
  for (int d4 = 0; d4 < 16; ++d4) {
    float4 v = a4[d4];
    ar[d4 * 4 + 0] = v.x;
    ar[d4 * 4 + 1] = v.y;
    ar[d4 * 4 + 2] = v.z;
    ar[d4 * 4 + 3] = v.w;
  }
  float outv[NO];
#pragma unroll
  for (int oo = 0; oo < NO; ++oo) outv[oo] = b2s[oo];
#pragma unroll 2
  for (int o = 0; o < NHID; ++o) {
    float acc = b1s[o];
    const float4* w4 = (const float4*)&w1s[o * 64];
#pragma unroll
    for (int i4 = 0; i4 < 16; ++i4) {
      float4 ww = w4[i4];
      acc += ar[i4 * 4 + 0] * ww.x + ar[i4 * 4 + 1] * ww.y +
             ar[i4 * 4 + 2] * ww.z + ar[i4 * 4 + 3] * ww.w;
    }
    const float hv = fmaxf(acc, 0.f);
#pragma unroll
    for (int oo = 0; oo < NO; ++oo) outv[oo] += hv * w2s[oo * NHID + o];
  }
  float* orow = out + (size_t)row * NO;
#pragma unroll
  for (int oo = 0; oo < NO; ++oo) orow[oo] = outv[oo];
}

extern "C" void kernel_launch(void* const* d_in, const int* in_sizes, int n_in,
                              void* d_out, int out_size, void* d_ws, size_t ws_size,
                              hipStream_t stream) {
  const float* z = (const float*)d_in[0];
  const float* ts = (const float*)d_in[1];
  const float* refq = (const float*)d_in[2];
  const float* Wih_f = (const float*)d_in[3];
  const float* Whh_f = (const float*)d_in[4];
  const float* bih_f = (const float*)d_in[5];
  const float* bhh_f = (const float*)d_in[6];
  const float* Wih_b = (const float*)d_in[7];
  const float* Whh_b = (const float*)d_in[8];
  const float* bih_b = (const float*)d_in[9];
  const float* bhh_b = (const float*)d_in[10];
  const float* Wq = (const float*)d_in[11];
  const float* bq = (const float*)d_in[12];
  const float* Wk = (const float*)d_in[13];
  const float* bk = (const float*)d_in[14];
  const float* Wv = (const float*)d_in[15];
  const float* bv = (const float*)d_in[16];
  const float* W1 = (const float*)d_in[17];
  const float* b1 = (const float*)d_in[18];
  const float* W2 = (const float*)d_in[19];
  const float* b2 = (const float*)d_in[20];

  float* ws = (float*)d_ws;
  float* gi = ws;               // 3,145,728 (overlaid with att)
  float* att = ws;              // 4,194,304
  float* val = ws + 4194304;    // 1,048,576
  float* ktab = ws + 5242880;   // 8,192
  float* w1p = ws + 5251072;    // 3,200
  float* b1p = ws + 5254272;    // 64
  float* out = (float*)d_out;

  prep_kernel<<<3, 256, 0, stream>>>(refq, Wk, bk, Wv, bv, W1, b1,
                                     ktab, w1p, b1p);
  prep_gi_kernel<<<128, 256, 0, stream>>>(z, Wih_f, bih_f, bhh_f,
                                          Wih_b, bih_b, bhh_b, gi);
  gru_kernel<<<64, 64, 0, stream>>>(gi, Whh_f, bhh_f, Whh_b, bhh_b, val);
  attn_core_kernel<<<256, 256, 0, stream>>>(ts, ktab, val, Wq, bq, att);
  mlp_kernel<<<256, 256, 0, stream>>>(att, w1p, b1p, W2, b2, out);
}

// Round 11
// 475.895 us; speedup vs baseline: 1.0333x; 1.0333x over previous
//
#include <hip/hip_runtime.h>
#include <hip/hip_bf16.h>
#include <math.h>

#define NB 32
#define NQ 2048
#define NK 512
#define NE 16
#define NH 32
#define NL 20
#define NHID 50
#define NO 41

// ws layout (floats):
// gi   : [64][512][96] @ 0        (3,145,728)  OVERLAID with att (gru before attn)
// att  : [65536][64]   @ 0        (4,194,304)  normalized P@val (pre-Wv)
// val  : [32][512][64] @ 4194304  (1,048,576)
// ktab : [512][16]     @ 5242880  (8,192)
// w1p  : [50][64]      @ 5251072  (3,200)      W1 @ Wv
// b1p  : [50]          @ 5254272  (64)         b1 + W1 @ bv
// total ~21.0 MB (proven size)

__device__ __forceinline__ float fsigmoid(float x) {
  return __builtin_amdgcn_rcpf(1.0f + __expf(-x));
}
__device__ __forceinline__ float ftanh(float x) {
  return 1.0f - 2.0f * __builtin_amdgcn_rcpf(__expf(2.0f * x) + 1.0f);
}
__device__ __forceinline__ float bperm(int lane, float v) {
  return __builtin_bit_cast(
      float, __builtin_amdgcn_ds_bpermute(lane << 2, __builtin_bit_cast(int, v)));
}

// blocks 0-1: k-table. block 2: fold Wv into W1.
__global__ __launch_bounds__(256) void prep_kernel(
    const float* __restrict__ refq, const float* __restrict__ Wk,
    const float* __restrict__ bk,
    const float* __restrict__ Wv, const float* __restrict__ bv,
    const float* __restrict__ W1, const float* __restrict__ b1,
    float* __restrict__ ktab, float* __restrict__ w1p,
    float* __restrict__ b1p) {
  const int tid = threadIdx.x;
  if (blockIdx.x < 2) {
    const int r = blockIdx.x * 256 + tid;
    const float divs[8] = {1.0f, 0.74989421f, 0.56234133f, 0.42169650f,
                           0.31622777f, 0.23713737f, 0.17782794f, 0.13335214f};
    float pos = refq[r];
    float emb[NE];
#pragma unroll
    for (int m = 0; m < 8; ++m) {
      float a = 48.0f * pos * divs[m];
      emb[2 * m] = sinf(a);
      emb[2 * m + 1] = cosf(a);
    }
#pragma unroll
    for (int e = 0; e < NE; ++e) {
      float acc = bk[e];
#pragma unroll
      for (int i = 0; i < NE; ++i) acc += emb[i] * Wk[e * NE + i];
      ktab[r * NE + e] = acc;
    }
  } else {
    for (int e = tid; e < NHID * 64; e += 256) {
      const int o = e >> 6, i = e & 63;
      float acc = 0.f;
#pragma unroll 4
      for (int d = 0; d < 64; ++d) acc += W1[o * 64 + d] * Wv[d * 64 + i];
      w1p[e] = acc;
    }
    if (tid < NHID) {
      float acc = b1[tid];
#pragma unroll 4
      for (int d = 0; d < 64; ++d) acc += W1[tid * 64 + d] * bv[d];
      b1p[tid] = acc;
    }
  }
}

// Input-side gates, fully parallel: gi[c][t][g] = z[b][t] . Wih[g] + bih[g]
// (+ bhh[g] folded for the r,z gates).
__global__ __launch_bounds__(256) void prep_gi_kernel(
    const float* __restrict__ z,
    const float* __restrict__ Wih_f, const float* __restrict__ bih_f,
    const float* __restrict__ bhh_f,
    const float* __restrict__ Wih_b, const float* __restrict__ bih_b,
    const float* __restrict__ bhh_b, float* __restrict__ gi) {
  const int row = blockIdx.x * 256 + threadIdx.x;  // chain*512 + t
  const int c = row >> 9, t = row & 511;
  const int dir = c >> 5, b = c & 31;
  const float* __restrict__ Wih = dir ? Wih_b : Wih_f;
  const float* __restrict__ bih = dir ? bih_b : bih_f;
  const float* __restrict__ bhh = dir ? bhh_b : bhh_f;
  const float* __restrict__ zr = z + ((size_t)b * NK + t) * NL;
  float x[NL];
#pragma unroll
  for (int i = 0; i < NL; ++i) x[i] = zr[i];
  float* __restrict__ go = gi + (size_t)row * 96;
  for (int g = 0; g < 96; ++g) {
    float acc = bih[g] + (g < 64 ? bhh[g] : 0.f);
#pragma unroll
    for (int i = 0; i < NL; ++i) acc += x[i] * Wih[g * NL + i];
    go[g] = acc;
  }
}

// Serial GRU, ONE DS round per step and ZERO cross-lane combines:
// 2 chains per wave (lane half = chain); each lane owns unit j of its chain
// and computes FULL 32-length dots for all 3 gates (96 FMA — cheaper than a
// second DS round-trip at 1-wave/CU latencies). h-gather: 1 ds_write + 8
// broadcast ds_read_b128 (same-wave LDS is in-order; proven rounds 4-8).
__global__ __launch_bounds__(64) void gru_kernel(
    const float* __restrict__ gi,
    const float* __restrict__ Whh_f, const float* __restrict__ bhh_f,
    const float* __restrict__ Whh_b, const float* __restrict__ bhh_b,
    float* __restrict__ val) {
  __shared__ __align__(16) float hbuf[64];  // [chain-half][32]
  const int l = threadIdx.x;
  const int j = l & 31, half = l >> 5;
  const int c = blockIdx.x * 2 + half;   // 2|32 => both halves same dir
  const int dir = c >> 5, b = c & 31;
  const int hb = half * 32;
  const float* __restrict__ Whh = dir ? Whh_b : Whh_f;
  const float* __restrict__ bhh = dir ? bhh_b : bhh_f;

  float wr[32], wz[32], wn[32];
#pragma unroll
  for (int i = 0; i < 32; ++i) {
    wr[i] = Whh[j * 32 + i];
    wz[i] = Whh[(j + 32) * 32 + i];
    wn[i] = Whh[(j + 64) * 32 + i];
  }
  const float bhn = bhh[j + 64];
  float h = 0.f;
  hbuf[l] = 0.f;
  const float* __restrict__ gic = gi + (size_t)c * NK * 96;

  float r0, z0, n0, r1, z1, n1, r2, z2, n2, r3, z3, n3;
  auto giload = [&](int s, float& gr, float& gz, float& gn) {
    const int tt = dir ? (NK - 1 - s) : s;
    gr = gic[tt * 96 + j];
    gz = gic[tt * 96 + 32 + j];
    gn = gic[tt * 96 + 64 + j];
  };
  giload(0, r0, z0, n0);
  giload(1, r1, z1, n1);
  giload(2, r2, z2, n2);
  giload(3, r3, z3, n3);

  auto step = [&](int s, float& gr, float& gz, float& gn) {
    const float gir = gr, giz = gz, gin = gn;
    if (s + 4 < NK) giload(s + 4, gr, gz, gn);  // global prefetch (vmcnt)
    // ONE DS round: write own h, read the chain's 32 h's as 8 b128 broadcasts
    hbuf[l] = h;
    float hv[32];
#pragma unroll
    for (int t = 0; t < 8; ++t) {
      const float4 hq = *(const float4*)&hbuf[hb + t * 4];
      hv[t * 4 + 0] = hq.x;
      hv[t * 4 + 1] = hq.y;
      hv[t * 4 + 2] = hq.z;
      hv[t * 4 + 3] = hq.w;
    }
    float sr0 = 0.f, sr1 = 0.f, sz0 = 0.f, sz1 = 0.f, sn0 = 0.f, sn1 = 0.f;
#pragma unroll
    for (int t = 0; t < 16; ++t) {
      sr0 += wr[t] * hv[t];
      sz0 += wz[t] * hv[t];
      sn0 += wn[t] * hv[t];
      sr1 += wr[16 + t] * hv[16 + t];
      sz1 += wz[16 + t] * hv[16 + t];
      sn1 += wn[16 + t] * hv[16 + t];
    }
    const float rg = fsigmoid(gir + sr0 + sr1);            // biases in gi
    const float ug = fsigmoid(giz + sz0 + sz1);
    const float ng = ftanh(gin + rg * (sn0 + sn1 + bhn));
    h = ng + ug * (h - ng);
    const int tt = dir ? (NK - 1 - s) : s;
    val[((size_t)b * NK + tt) * 64 + dir * 32 + j] = h;
  };
  for (int s = 0; s < NK; s += 4) {
    step(s, r0, z0, n0);
    step(s + 1, r1, z1, n1);
    step(s + 2, r2, z2, n2);
    step(s + 3, r3, z3, n3);
  }
}

// R=8 register-reuse attention (unchanged from round 9, PASSED).
__global__ __launch_bounds__(256) void attn_core_kernel(
    const float* __restrict__ tsteps, const float* __restrict__ ktab,
    const float* __restrict__ val,
    const float* __restrict__ Wq, const float* __restrict__ bq,
    float* __restrict__ att) {
  __shared__ __align__(16) float kts[NK * NE + 32];  // skewed, 33 KB
  __shared__ float wqs[NE * NE];
  __shared__ float bqs[NE];
  const int tid = threadIdx.x;
  for (int i = tid; i < NK * NE; i += 256) {
    const int k = i >> 4, e = i & 15;
    kts[(k << 4) + ((k >> 6) << 2) + e] = ktab[i];
  }
  for (int i = tid; i < NE * NE; i += 256) wqs[i] = Wq[i];
  if (tid < NE) bqs[tid] = bq[tid];
  __syncthreads();

  const int lane = tid & 63;
  const int g = lane >> 3;      // group 0..7
  const int r8 = lane & 7;      // row-in-group for scoring; d-eighth for acc
  const int wave = tid >> 6;
  const int rowbase = blockIdx.x * 256 + wave * 64 + g * 8;
  const int myrow = rowbase + r8;
  const int b = myrow >> 11;    // uniform per wave (64-row span, 64|2048)

  const float pos = tsteps[myrow];
  const float divs[8] = {1.0f, 0.74989421f, 0.56234133f, 0.42169650f,
                         0.31622777f, 0.23713737f, 0.17782794f, 0.13335214f};
  float emb[NE];
#pragma unroll
  for (int m = 0; m < 8; ++m) {
    float a = 48.0f * pos * divs[m];
    emb[2 * m] = sinf(a);
    emb[2 * m + 1] = cosf(a);
  }
  float q[NE];
#pragma unroll
  for (int e = 0; e < NE; ++e) {
    float acc = bqs[e];
#pragma unroll
    for (int i = 0; i < NE; ++i) acc += emb[i] * wqs[e * NE + i];
    q[e] = acc * 0.25f;  // fold 1/sqrt(E)
  }
  const int lb = lane & ~7;  // group's lane 0
  const float* __restrict__ vb = val + (size_t)b * NK * 64;

  float acc[8][8];
#pragma unroll
  for (int m = 0; m < 8; ++m)
#pragma unroll
    for (int d = 0; d < 8; ++d) acc[m][d] = 0.f;
  float lsum = 0.f;

  for (int kb = 0; kb < 8; ++kb) {
    const int khi = (g + kb) & 7;
    const float* __restrict__ kbase = &kts[(khi << 10) + (khi << 2)];
    const float* __restrict__ vkb = vb + (size_t)(khi << 6) * 64 + r8 * 8;
#pragma unroll 2
    for (int i = 0; i < 64; ++i) {
      const float4* kr = (const float4*)(kbase + i * 16);  // group-broadcast
      const float4 k0 = kr[0], k1 = kr[1], k2 = kr[2], k3 = kr[3];
      float s;
      s  = q[0] * k0.x + q[1] * k0.y + q[2] * k0.z + q[3] * k0.w;
      s += q[4] * k1.x + q[5] * k1.y + q[6] * k1.z + q[7] * k1.w;
      s += q[8] * k2.x + q[9] * k2.y + q[10] * k2.z + q[11] * k2.w;
      s += q[12] * k3.x + q[13] * k3.y + q[14] * k3.z + q[15] * k3.w;
      const float p = __expf(s);  // scores O(1): no max-sub needed
      lsum += p;
      const float* vr = vkb + i * 64;
      const float4 va = *(const float4*)(vr);
      const float4 vb4 = *(const float4*)(vr + 4);
      float pm[8];
#pragma unroll
      for (int m = 0; m < 8; ++m) pm[m] = bperm(lb + m, p);
#pragma unroll
      for (int m = 0; m < 8; ++m) {
        acc[m][0] += pm[m] * va.x;  acc[m][1] += pm[m] * va.y;
        acc[m][2] += pm[m] * va.z;  acc[m][3] += pm[m] * va.w;
        acc[m][4] += pm[m] * vb4.x; acc[m][5] += pm[m] * vb4.y;
        acc[m][6] += pm[m] * vb4.z; acc[m][7] += pm[m] * vb4.w;
      }
    }
  }
  float* ob = att + (size_t)rowbase * 64 + r8 * 8;
#pragma unroll
  for (int m = 0; m < 8; ++m) {
    const float im = 1.0f / bperm(lb + m, lsum);
    float4 o;
    o.x = acc[m][0] * im; o.y = acc[m][1] * im;
    o.z = acc[m][2] * im; o.w = acc[m][3] * im;
    *(float4*)(ob + m * 64) = o;
    o.x = acc[m][4] * im; o.y = acc[m][5] * im;
    o.z = acc[m][6] * im; o.w = acc[m][7] * im;
    *(float4*)(ob + m * 64 + 4) = o;
  }
}

// Per-row MLP on folded weights: out = W2 @ relu(W1' @ ar + b1') + b2.
__global__ __launch_bounds__(256) void mlp_kernel(
    const float* __restrict__ att,
    const float* __restrict__ w1p, const float* __restrict__ b1p,
    const float* __restrict__ W2, const float* __restrict__ b2,
    float* __restrict__ out) {
  __shared__ __align__(16) float w1s[NHID * 64];   // 12.8 KB
  __shared__ __align__(16) float w2s[NO * NHID];   // 8.2 KB
  __shared__ float b1s[NHID], b2s[NO];
  const int tid = threadIdx.x;
  for (int i = tid; i < NHID * 64; i += 256) w1s[i] = w1p[i];
  for (int i = tid; i < NO * NHID; i += 256) w2s[i] = W2[i];
  if (tid < NHID) b1s[tid] = b1p[tid];
  if (tid < NO) b2s[tid] = b2[tid];
  __syncthreads();

  const int row = blockIdx.x * 256 + tid;
  float ar[64];
  const float4* a4 = (const float4*)(att + (size_t)row * 64);
#pragma unroll
  for (int d4 = 0; d4 < 16; ++d4) {
    float4 v = a4[d4];
    ar[d4 * 4 + 0] = v.x;
    ar[d4 * 4 + 1] = v.y;
    ar[d4 * 4 + 2] = v.z;
    ar[d4 * 4 + 3] = v.w;
  }
  float outv[NO];
#pragma unroll
  for (int oo = 0; oo < NO; ++oo) outv[oo] = b2s[oo];
#pragma unroll 2
  for (int o = 0; o < NHID; ++o) {
    float acc = b1s[o];
    const float4* w4 = (const float4*)&w1s[o * 64];
#pragma unroll
    for (int i4 = 0; i4 < 16; ++i4) {
      float4 ww = w4[i4];
      acc += ar[i4 * 4 + 0] * ww.x + ar[i4 * 4 + 1] * ww.y +
             ar[i4 * 4 + 2] * ww.z + ar[i4 * 4 + 3] * ww.w;
    }
    const float hv = fmaxf(acc, 0.f);
#pragma unroll
    for (int oo = 0; oo < NO; ++oo) outv[oo] += hv * w2s[oo * NHID + o];
  }
  float* orow = out + (size_t)row * NO;
#pragma unroll
  for (int oo = 0; oo < NO; ++oo) orow[oo] = outv[oo];
}

extern "C" void kernel_launch(void* const* d_in, const int* in_sizes, int n_in,
                              void* d_out, int out_size, void* d_ws, size_t ws_size,
                              hipStream_t stream) {
  const float* z = (const float*)d_in[0];
  const float* ts = (const float*)d_in[1];
  const float* refq = (const float*)d_in[2];
  const float* Wih_f = (const float*)d_in[3];
  const float* Whh_f = (const float*)d_in[4];
  const float* bih_f = (const float*)d_in[5];
  const float* bhh_f = (const float*)d_in[6];
  const float* Wih_b = (const float*)d_in[7];
  const float* Whh_b = (const float*)d_in[8];
  const float* bih_b = (const float*)d_in[9];
  const float* bhh_b = (const float*)d_in[10];
  const float* Wq = (const float*)d_in[11];
  const float* bq = (const float*)d_in[12];
  const float* Wk = (const float*)d_in[13];
  const float* bk = (const float*)d_in[14];
  const float* Wv = (const float*)d_in[15];
  const float* bv = (const float*)d_in[16];
  const float* W1 = (const float*)d_in[17];
  const float* b1 = (const float*)d_in[18];
  const float* W2 = (const float*)d_in[19];
  const float* b2 = (const float*)d_in[20];

  float* ws = (float*)d_ws;
  float* gi = ws;               // 3,145,728 (overlaid with att)
  float* att = ws;              // 4,194,304
  float* val = ws + 4194304;    // 1,048,576
  float* ktab = ws + 5242880;   // 8,192
  float* w1p = ws + 5251072;    // 3,200
  float* b1p = ws + 5254272;    // 64
  float* out = (float*)d_out;

  prep_kernel<<<3, 256, 0, stream>>>(refq, Wk, bk, Wv, bv, W1, b1,
                                     ktab, w1p, b1p);
  prep_gi_kernel<<<128, 256, 0, stream>>>(z, Wih_f, bih_f, bhh_f,
                                          Wih_b, bih_b, bhh_b, gi);
  gru_kernel<<<32, 64, 0, stream>>>(gi, Whh_f, bhh_f, Whh_b, bhh_b, val);
  attn_core_kernel<<<256, 256, 0, stream>>>(ts, ktab, val, Wq, bq, att);
  mlp_kernel<<<256, 256, 0, stream>>>(att, w1p, b1p, W2, b2, out);
}

// Round 12
// 415.621 us; speedup vs baseline: 1.1832x; 1.1450x over previous
//
#include <hip/hip_runtime.h>
#include <hip/hip_bf16.h>
#include <math.h>

#define NB 32
#define NQ 2048
#define NK 512
#define NE 16
#define NH 32
#define NL 20
#define NHID 50
#define NO 41

// ws layout (floats):
// gi   : [64][512][96] @ 0        (3,145,728)  OVERLAID with att (gru before attn)
// att  : [65536][64]   @ 0        (4,194,304)  normalized P@val (pre-Wv)
// val  : [32][512][64] @ 4194304  (1,048,576)
// ktab : [512][16]     @ 5242880  (8,192)
// w1p  : [50][64]      @ 5251072  (3,200)      W1 @ Wv
// b1p  : [50]          @ 5254272  (64)         b1 + W1 @ bv
// total ~21.0 MB (proven size)

__device__ __forceinline__ float fsigmoid(float x) {
  return __builtin_amdgcn_rcpf(1.0f + __expf(-x));
}
__device__ __forceinline__ float ftanh(float x) {
  return 1.0f - 2.0f * __builtin_amdgcn_rcpf(__expf(2.0f * x) + 1.0f);
}
__device__ __forceinline__ float bperm(int lane, float v) {
  return __builtin_bit_cast(
      float, __builtin_amdgcn_ds_bpermute(lane << 2, __builtin_bit_cast(int, v)));
}

// blocks 0-1: k-table. block 2: fold Wv into W1.
__global__ __launch_bounds__(256) void prep_kernel(
    const float* __restrict__ refq, const float* __restrict__ Wk,
    const float* __restrict__ bk,
    const float* __restrict__ Wv, const float* __restrict__ bv,
    const float* __restrict__ W1, const float* __restrict__ b1,
    float* __restrict__ ktab, float* __restrict__ w1p,
    float* __restrict__ b1p) {
  const int tid = threadIdx.x;
  if (blockIdx.x < 2) {
    const int r = blockIdx.x * 256 + tid;
    const float divs[8] = {1.0f, 0.74989421f, 0.56234133f, 0.42169650f,
                           0.31622777f, 0.23713737f, 0.17782794f, 0.13335214f};
    float pos = refq[r];
    float emb[NE];
#pragma unroll
    for (int m = 0; m < 8; ++m) {
      float a = 48.0f * pos * divs[m];
      emb[2 * m] = sinf(a);
      emb[2 * m + 1] = cosf(a);
    }
#pragma unroll
    for (int e = 0; e < NE; ++e) {
      float acc = bk[e];
#pragma unroll
      for (int i = 0; i < NE; ++i) acc += emb[i] * Wk[e * NE + i];
      ktab[r * NE + e] = acc;
    }
  } else {
    for (int e = tid; e < NHID * 64; e += 256) {
      const int o = e >> 6, i = e & 63;
      float acc = 0.f;
#pragma unroll 4
      for (int d = 0; d < 64; ++d) acc += W1[o * 64 + d] * Wv[d * 64 + i];
      w1p[e] = acc;
    }
    if (tid < NHID) {
      float acc = b1[tid];
#pragma unroll 4
      for (int d = 0; d < 64; ++d) acc += W1[tid * 64 + d] * bv[d];
      b1p[tid] = acc;
    }
  }
}

// Input-side gates, fully parallel.
__global__ __launch_bounds__(256) void prep_gi_kernel(
    const float* __restrict__ z,
    const float* __restrict__ Wih_f, const float* __restrict__ bih_f,
    const float* __restrict__ bhh_f,
    const float* __restrict__ Wih_b, const float* __restrict__ bih_b,
    const float* __restrict__ bhh_b, float* __restrict__ gi) {
  const int row = blockIdx.x * 256 + threadIdx.x;  // chain*512 + t
  const int c = row >> 9, t = row & 511;
  const int dir = c >> 5, b = c & 31;
  const float* __restrict__ Wih = dir ? Wih_b : Wih_f;
  const float* __restrict__ bih = dir ? bih_b : bih_f;
  const float* __restrict__ bhh = dir ? bhh_b : bhh_f;
  const float* __restrict__ zr = z + ((size_t)b * NK + t) * NL;
  float x[NL];
#pragma unroll
  for (int i = 0; i < NL; ++i) x[i] = zr[i];
  float* __restrict__ go = gi + (size_t)row * 96;
  for (int g = 0; g < 96; ++g) {
    float acc = bih[g] + (g < 64 ? bhh[g] : 0.f);
#pragma unroll
    for (int i = 0; i < NL; ++i) acc += x[i] * Wih[g * NL + i];
    go[g] = acc;
  }
}

// Serial GRU (round-11, PASSED): 2 chains per wave, full 32-dots per lane,
// ONE DS round per step, zero cross-lane combines.
__global__ __launch_bounds__(64) void gru_kernel(
    const float* __restrict__ gi,
    const float* __restrict__ Whh_f, const float* __restrict__ bhh_f,
    const float* __restrict__ Whh_b, const float* __restrict__ bhh_b,
    float* __restrict__ val) {
  __shared__ __align__(16) float hbuf[64];  // [chain-half][32]
  const int l = threadIdx.x;
  const int j = l & 31, half = l >> 5;
  const int c = blockIdx.x * 2 + half;   // 2|32 => both halves same dir
  const int dir = c >> 5, b = c & 31;
  const int hb = half * 32;
  const float* __restrict__ Whh = dir ? Whh_b : Whh_f;
  const float* __restrict__ bhh = dir ? bhh_b : bhh_f;

  float wr[32], wz[32], wn[32];
#pragma unroll
  for (int i = 0; i < 32; ++i) {
    wr[i] = Whh[j * 32 + i];
    wz[i] = Whh[(j + 32) * 32 + i];
    wn[i] = Whh[(j + 64) * 32 + i];
  }
  const float bhn = bhh[j + 64];
  float h = 0.f;
  hbuf[l] = 0.f;
  const float* __restrict__ gic = gi + (size_t)c * NK * 96;

  float r0, z0, n0, r1, z1, n1, r2, z2, n2, r3, z3, n3;
  auto giload = [&](int s, float& gr, float& gz, float& gn) {
    const int tt = dir ? (NK - 1 - s) : s;
    gr = gic[tt * 96 + j];
    gz = gic[tt * 96 + 32 + j];
    gn = gic[tt * 96 + 64 + j];
  };
  giload(0, r0, z0, n0);
  giload(1, r1, z1, n1);
  giload(2, r2, z2, n2);
  giload(3, r3, z3, n3);

  auto step = [&](int s, float& gr, float& gz, float& gn) {
    const float gir = gr, giz = gz, gin = gn;
    if (s + 4 < NK) giload(s + 4, gr, gz, gn);  // global prefetch (vmcnt)
    hbuf[l] = h;
    float hv[32];
#pragma unroll
    for (int t = 0; t < 8; ++t) {
      const float4 hq = *(const float4*)&hbuf[hb + t * 4];
      hv[t * 4 + 0] = hq.x;
      hv[t * 4 + 1] = hq.y;
      hv[t * 4 + 2] = hq.z;
      hv[t * 4 + 3] = hq.w;
    }
    float sr0 = 0.f, sr1 = 0.f, sz0 = 0.f, sz1 = 0.f, sn0 = 0.f, sn1 = 0.f;
#pragma unroll
    for (int t = 0; t < 16; ++t) {
      sr0 += wr[t] * hv[t];
      sz0 += wz[t] * hv[t];
      sn0 += wn[t] * hv[t];
      sr1 += wr[16 + t] * hv[16 + t];
      sz1 += wz[16 + t] * hv[16 + t];
      sn1 += wn[16 + t] * hv[16 + t];
    }
    const float rg = fsigmoid(gir + sr0 + sr1);            // biases in gi
    const float ug = fsigmoid(giz + sz0 + sz1);
    const float ng = ftanh(gin + rg * (sn0 + sn1 + bhn));
    h = ng + ug * (h - ng);
    const int tt = dir ? (NK - 1 - s) : s;
    val[((size_t)b * NK + tt) * 64 + dir * 32 + j] = h;
  };
  for (int s = 0; s < NK; s += 4) {
    step(s, r0, z0, n0);
    step(s + 1, r1, z1, n1);
    step(s + 2, r2, z2, n2);
    step(s + 3, r3, z3, n3);
  }
}

// R=8 attention v2: 4 waves per block share the SAME 64 rows; wave w covers
// k-quarter {khi = 2w, 2w+1}; partials combined via LDS. Per-group k-offset
// ii=(i+g*8)&63 + skew ((k>>3)&7)<<2 puts the 8 groups on disjoint kt bank
// quads and 8 distinct v rows per load instruction (1 KB fully distinct).
__global__ __launch_bounds__(256) void attn_core_kernel(
    const float* __restrict__ tsteps, const float* __restrict__ ktab,
    const float* __restrict__ val,
    const float* __restrict__ Wq, const float* __restrict__ bq,
    float* __restrict__ att) {
  __shared__ __align__(16) float kts[NK * NE + 64];  // skewed, 33 KB
  __shared__ __align__(16) float cbuf[4][64][16];    // 16 KB combine buffer
  __shared__ float lbuf[4][64];                      // 1 KB lsum partials
  __shared__ float wqs[NE * NE];
  __shared__ float bqs[NE];
  const int tid = threadIdx.x;
  for (int i = tid; i < NK * NE; i += 256) {
    const int k = i >> 4, e = i & 15;
    kts[(k << 4) + (((k >> 3) & 7) << 2) + e] = ktab[i];
  }
  for (int i = tid; i < NE * NE; i += 256) wqs[i] = Wq[i];
  if (tid < NE) bqs[tid] = bq[tid];
  __syncthreads();

  const int lane = tid & 63;
  const int g = lane >> 3;      // group 0..7
  const int r8 = lane & 7;      // row-in-group for scoring; d-eighth for acc
  const int wave = tid >> 6;    // k-quarter owner
  const int rowbase = blockIdx.x * 64 + g * 8;
  const int myrow = rowbase + r8;
  const int b = myrow >> 11;    // uniform per block (64-row span, 64|2048)

  const float pos = tsteps[myrow];
  const float divs[8] = {1.0f, 0.74989421f, 0.56234133f, 0.42169650f,
                         0.31622777f, 0.23713737f, 0.17782794f, 0.13335214f};
  float emb[NE];
#pragma unroll
  for (int m = 0; m < 8; ++m) {
    float a = 48.0f * pos * divs[m];
    emb[2 * m] = sinf(a);
    emb[2 * m + 1] = cosf(a);
  }
  float q[NE];
#pragma unroll
  for (int e = 0; e < NE; ++e) {
    float acc = bqs[e];
#pragma unroll
    for (int i = 0; i < NE; ++i) acc += emb[i] * wqs[e * NE + i];
    q[e] = acc * 0.25f;  // fold 1/sqrt(E)
  }
  const int lb = lane & ~7;  // group's lane 0
  const float* __restrict__ vb = val + (size_t)b * NK * 64;

  float acc[8][8];
#pragma unroll
  for (int m = 0; m < 8; ++m)
#pragma unroll
    for (int d = 0; d < 8; ++d) acc[m][d] = 0.f;
  float lsum = 0.f;

#pragma unroll
  for (int kb = 0; kb < 2; ++kb) {
    const int khi = (wave << 1) | kb;   // this wave's k-block (uniform)
#pragma unroll 2
    for (int i = 0; i < 64; ++i) {
      const int ii = (i + g * 8) & 63;  // group stagger (uniform in group)
      const int k = (khi << 6) | ii;
      const float4* kr =
          (const float4*)&kts[(k << 4) + (((k >> 3) & 7) << 2)];
      const float4 k0 = kr[0], k1 = kr[1], k2 = kr[2], k3 = kr[3];
      float s;
      s  = q[0] * k0.x + q[1] * k0.y + q[2] * k0.z + q[3] * k0.w;
      s += q[4] * k1.x + q[5] * k1.y + q[6] * k1.z + q[7] * k1.w;
      s += q[8] * k2.x + q[9] * k2.y + q[10] * k2.z + q[11] * k2.w;
      s += q[12] * k3.x + q[13] * k3.y + q[14] * k3.z + q[15] * k3.w;
      const float p = __expf(s);  // scores O(1): no max-sub needed
      lsum += p;
      const float* vr = vb + (size_t)k * 64 + r8 * 8;
      const float4 va = *(const float4*)(vr);
      const float4 vb4 = *(const float4*)(vr + 4);
      float pm[8];
#pragma unroll
      for (int m = 0; m < 8; ++m) pm[m] = bperm(lb + m, p);
#pragma unroll
      for (int m = 0; m < 8; ++m) {
        acc[m][0] += pm[m] * va.x;  acc[m][1] += pm[m] * va.y;
        acc[m][2] += pm[m] * va.z;  acc[m][3] += pm[m] * va.w;
        acc[m][4] += pm[m] * vb4.x; acc[m][5] += pm[m] * vb4.y;
        acc[m][6] += pm[m] * vb4.z; acc[m][7] += pm[m] * vb4.w;
      }
    }
  }

  // cross-wave combine: 4 partials per (row, dim); lsum totals once.
  lbuf[wave][lane] = lsum;
  float lt = 0.f;
  float* ob = att + (size_t)rowbase * 64 + r8 * 8;
#pragma unroll
  for (int mm = 0; mm < 8; mm += 2) {
    *(float4*)&cbuf[wave][lane][0] =
        make_float4(acc[mm][0], acc[mm][1], acc[mm][2], acc[mm][3]);
    *(float4*)&cbuf[wave][lane][4] =
        make_float4(acc[mm][4], acc[mm][5], acc[mm][6], acc[mm][7]);
    *(float4*)&cbuf[wave][lane][8] =
        make_float4(acc[mm + 1][0], acc[mm + 1][1], acc[mm + 1][2],
                    acc[mm + 1][3]);
    *(float4*)&cbuf[wave][lane][12] =
        make_float4(acc[mm + 1][4], acc[mm + 1][5], acc[mm + 1][6],
                    acc[mm + 1][7]);
    __syncthreads();
    if (mm == 0)
      lt = lbuf[0][lane] + lbuf[1][lane] + lbuf[2][lane] + lbuf[3][lane];
    if (wave == 0) {
      float s[16];
#pragma unroll
      for (int d4 = 0; d4 < 4; ++d4) {
        const float4 c0 = *(const float4*)&cbuf[0][lane][d4 * 4];
        const float4 c1 = *(const float4*)&cbuf[1][lane][d4 * 4];
        const float4 c2 = *(const float4*)&cbuf[2][lane][d4 * 4];
        const float4 c3 = *(const float4*)&cbuf[3][lane][d4 * 4];
        s[d4 * 4 + 0] = c0.x + c1.x + c2.x + c3.x;
        s[d4 * 4 + 1] = c0.y + c1.y + c2.y + c3.y;
        s[d4 * 4 + 2] = c0.z + c1.z + c2.z + c3.z;
        s[d4 * 4 + 3] = c0.w + c1.w + c2.w + c3.w;
      }
      const float im0 = 1.0f / bperm(lb + mm, lt);
      const float im1 = 1.0f / bperm(lb + mm + 1, lt);
      *(float4*)(ob + mm * 64) =
          make_float4(s[0] * im0, s[1] * im0, s[2] * im0, s[3] * im0);
      *(float4*)(ob + mm * 64 + 4) =
          make_float4(s[4] * im0, s[5] * im0, s[6] * im0, s[7] * im0);
      *(float4*)(ob + (mm + 1) * 64) =
          make_float4(s[8] * im1, s[9] * im1, s[10] * im1, s[11] * im1);
      *(float4*)(ob + (mm + 1) * 64 + 4) =
          make_float4(s[12] * im1, s[13] * im1, s[14] * im1, s[15] * im1);
    }
    __syncthreads();
  }
}

// Per-row MLP on folded weights: out = W2 @ relu(W1' @ ar + b1') + b2.
__global__ __launch_bounds__(256) void mlp_kernel(
    const float* __restrict__ att,
    const float* __restrict__ w1p, const float* __restrict__ b1p,
    const float* __restrict__ W2, const float* __restrict__ b2,
    float* __restrict__ out) {
  __shared__ __align__(16) float w1s[NHID * 64];   // 12.8 KB
  __shared__ __align__(16) float w2s[NO * NHID];   // 8.2 KB
  __shared__ float b1s[NHID], b2s[NO];
  const int tid = threadIdx.x;
  for (int i = tid; i < NHID * 64; i += 256) w1s[i] = w1p[i];
  for (int i = tid; i < NO * NHID; i += 256) w2s[i] = W2[i];
  if (tid < NHID) b1s[tid] = b1p[tid];
  if (tid < NO) b2s[tid] = b2[tid];
  __syncthreads();

  const int row = blockIdx.x * 256 + tid;
  float ar[64];
  const float4* a4 = (const float4*)(att + (size_t)row * 64);
#pragma unroll
  for (int d4 = 0; d4 < 16; ++d4) {
    float4 v = a4[d4];
    ar[d4 * 4 + 0] = v.x;
    ar[d4 * 4 + 1] = v.y;
    ar[d4 * 4 + 2] = v.z;
    ar[d4 * 4 + 3] = v.w;
  }
  float outv[NO];
#pragma unroll
  for (int oo = 0; oo < NO; ++oo) outv[oo] = b2s[oo];
#pragma unroll 2
  for (int o = 0; o < NHID; ++o) {
    float acc = b1s[o];
    const float4* w4 = (const float4*)&w1s[o * 64];
#pragma unroll
    for (int i4 = 0; i4 < 16; ++i4) {
      float4 ww = w4[i4];
      acc += ar[i4 * 4 + 0] * ww.x + ar[i4 * 4 + 1] * ww.y +
             ar[i4 * 4 + 2] * ww.z + ar[i4 * 4 + 3] * ww.w;
    }
    const float hv = fmaxf(acc, 0.f);
#pragma unroll
    for (int oo = 0; oo < NO; ++oo) outv[oo] += hv * w2s[oo * NHID + o];
  }
  float* orow = out + (size_t)row * NO;
#pragma unroll
  for (int oo = 0; oo < NO; ++oo) orow[oo] = outv[oo];
}

extern "C" void kernel_launch(void* const* d_in, const int* in_sizes, int n_in,
                              void* d_out, int out_size, void* d_ws, size_t ws_size,
                              hipStream_t stream) {
  const float* z = (const float*)d_in[0];
  const float* ts = (const float*)d_in[1];
  const float* refq = (const float*)d_in[2];
  const float* Wih_f = (const float*)d_in[3];
  const float* Whh_f = (const float*)d_in[4];
  const float* bih_f = (const float*)d_in[5];
  const float* bhh_f = (const float*)d_in[6];
  const float* Wih_b = (const float*)d_in[7];
  const float* Whh_b = (const float*)d_in[8];
  const float* bih_b = (const float*)d_in[9];
  const float* bhh_b = (const float*)d_in[10];
  const float* Wq = (const float*)d_in[11];
  const float* bq = (const float*)d_in[12];
  const float* Wk = (const float*)d_in[13];
  const float* bk = (const float*)d_in[14];
  const float* Wv = (const float*)d_in[15];
  const float* bv = (const float*)d_in[16];
  const float* W1 = (const float*)d_in[17];
  const float* b1 = (const float*)d_in[18];
  const float* W2 = (const float*)d_in[19];
  const float* b2 = (const float*)d_in[20];

  float* ws = (float*)d_ws;
  float* gi = ws;               // 3,145,728 (overlaid with att)
  float* att = ws;              // 4,194,304
  float* val = ws + 4194304;    // 1,048,576
  float* ktab = ws + 5242880;   // 8,192
  float* w1p = ws + 5251072;    // 3,200
  float* b1p = ws + 5254272;    // 64
  float* out = (float*)d_out;

  prep_kernel<<<3, 256, 0, stream>>>(refq, Wk, bk, Wv, bv, W1, b1,
                                     ktab, w1p, b1p);
  prep_gi_kernel<<<128, 256, 0, stream>>>(z, Wih_f, bih_f, bhh_f,
                                          Wih_b, bih_b, bhh_b, gi);
  gru_kernel<<<32, 64, 0, stream>>>(gi, Whh_f, bhh_f, Whh_b, bhh_b, val);
  attn_core_kernel<<<1024, 256, 0, stream>>>(ts, ktab, val, Wq, bq, att);
  mlp_kernel<<<256, 256, 0, stream>>>(att, w1p, b1p, W2, b2, out);
}

// Round 13
// 356.040 us; speedup vs baseline: 1.3812x; 1.1673x over previous
//
#include <hip/hip_runtime.h>
#include <hip/hip_bf16.h>
#include <math.h>

#define NB 32
#define NQ 2048
#define NK 512
#define NE 16
#define NH 32
#define NL 20
#define NHID 50
#define NO 41

#define LOG2E 1.4426950408889634f
#define TWO_LOG2E 2.8853900817779268f

// ws layout (floats):
// gi   : [64][512][96] @ 0        (3,145,728)  OVERLAID with att (gru before attn)
// att  : [65536][64]   @ 0        (4,194,304)  normalized P@val (pre-Wv)
// val  : [32][512][64] @ 4194304  (1,048,576)
// ktab : [512][16]     @ 5242880  (8,192)
// w1p  : [50][64]      @ 5251072  (3,200)      W1 @ Wv
// b1p  : [50]          @ 5254272  (64)         b1 + W1 @ bv
// total ~21.0 MB (proven size)

typedef __attribute__((ext_vector_type(2))) float f32x2;

__device__ __forceinline__ float bperm(int lane, float v) {
  return __builtin_bit_cast(
      float, __builtin_amdgcn_ds_bpermute(lane << 2, __builtin_bit_cast(int, v)));
}

// blocks 0-1: k-table. block 2: fold Wv into W1.
__global__ __launch_bounds__(256) void prep_kernel(
    const float* __restrict__ refq, const float* __restrict__ Wk,
    const float* __restrict__ bk,
    const float* __restrict__ Wv, const float* __restrict__ bv,
    const float* __restrict__ W1, const float* __restrict__ b1,
    float* __restrict__ ktab, float* __restrict__ w1p,
    float* __restrict__ b1p) {
  const int tid = threadIdx.x;
  if (blockIdx.x < 2) {
    const int r = blockIdx.x * 256 + tid;
    const float divs[8] = {1.0f, 0.74989421f, 0.56234133f, 0.42169650f,
                           0.31622777f, 0.23713737f, 0.17782794f, 0.13335214f};
    float pos = refq[r];
    float emb[NE];
#pragma unroll
    for (int m = 0; m < 8; ++m) {
      float a = 48.0f * pos * divs[m];
      emb[2 * m] = sinf(a);
      emb[2 * m + 1] = cosf(a);
    }
#pragma unroll
    for (int e = 0; e < NE; ++e) {
      float acc = bk[e];
#pragma unroll
      for (int i = 0; i < NE; ++i) acc += emb[i] * Wk[e * NE + i];
      ktab[r * NE + e] = acc;
    }
  } else {
    for (int e = tid; e < NHID * 64; e += 256) {
      const int o = e >> 6, i = e & 63;
      float acc = 0.f;
#pragma unroll 4
      for (int d = 0; d < 64; ++d) acc += W1[o * 64 + d] * Wv[d * 64 + i];
      w1p[e] = acc;
    }
    if (tid < NHID) {
      float acc = b1[tid];
#pragma unroll 4
      for (int d = 0; d < 64; ++d) acc += W1[tid * 64 + d] * bv[d];
      b1p[tid] = acc;
    }
  }
}

// Input-side gates, fully parallel; pre-scaled for exp2-based activations:
// r,z gates x log2e; n gate x 2*log2e (matching scaled Whh rows in gru).
__global__ __launch_bounds__(256) void prep_gi_kernel(
    const float* __restrict__ z,
    const float* __restrict__ Wih_f, const float* __restrict__ bih_f,
    const float* __restrict__ bhh_f,
    const float* __restrict__ Wih_b, const float* __restrict__ bih_b,
    const float* __restrict__ bhh_b, float* __restrict__ gi) {
  const int row = blockIdx.x * 256 + threadIdx.x;  // chain*512 + t
  const int c = row >> 9, t = row & 511;
  const int dir = c >> 5, b = c & 31;
  const float* __restrict__ Wih = dir ? Wih_b : Wih_f;
  const float* __restrict__ bih = dir ? bih_b : bih_f;
  const float* __restrict__ bhh = dir ? bhh_b : bhh_f;
  const float* __restrict__ zr = z + ((size_t)b * NK + t) * NL;
  float x[NL];
#pragma unroll
  for (int i = 0; i < NL; ++i) x[i] = zr[i];
  float* __restrict__ go = gi + (size_t)row * 96;
  for (int g = 0; g < 96; ++g) {
    float acc = bih[g] + (g < 64 ? bhh[g] : 0.f);
#pragma unroll
    for (int i = 0; i < NL; ++i) acc += x[i] * Wih[g * NL + i];
    go[g] = acc * (g < 64 ? LOG2E : TWO_LOG2E);
  }
}

// Serial GRU (round-11 structure, PASSED) + exp2-folded activations +
// packed dual-FMA dots + pointer-walked gi loads / val stores.
__global__ __launch_bounds__(64) void gru_kernel(
    const float* __restrict__ gi,
    const float* __restrict__ Whh_f, const float* __restrict__ bhh_f,
    const float* __restrict__ Whh_b, const float* __restrict__ bhh_b,
    float* __restrict__ val) {
  __shared__ __align__(16) float hbuf[64];  // [chain-half][32]
  const int l = threadIdx.x;
  const int j = l & 31, half = l >> 5;
  const int c = blockIdx.x * 2 + half;   // 2|32 => both halves same dir
  const int dir = c >> 5, b = c & 31;
  const int hb = half * 32;
  const float* __restrict__ Whh = dir ? Whh_b : Whh_f;
  const float* __restrict__ bhh = dir ? bhh_b : bhh_f;

  // weights pre-scaled: r,z x log2e; n x 2*log2e (gi scaled to match)
  f32x2 wr[16], wz[16], wn[16];
#pragma unroll
  for (int i = 0; i < 16; ++i) {
    wr[i] = f32x2{Whh[j * 32 + 2 * i], Whh[j * 32 + 2 * i + 1]} * LOG2E;
    wz[i] = f32x2{Whh[(j + 32) * 32 + 2 * i], Whh[(j + 32) * 32 + 2 * i + 1]} *
            LOG2E;
    wn[i] = f32x2{Whh[(j + 64) * 32 + 2 * i], Whh[(j + 64) * 32 + 2 * i + 1]} *
            TWO_LOG2E;
  }
  const float bhn = bhh[j + 64] * TWO_LOG2E;
  float h = 0.f;
  hbuf[l] = 0.f;

  const float* __restrict__ gic = gi + (size_t)c * NK * 96;
  const int gstart = dir ? (NK - 1) * 96 : 0;
  const int gstride = dir ? -96 : 96;
  float* __restrict__ vp =
      val + ((size_t)b * NK + (dir ? NK - 1 : 0)) * 64 + dir * 32 + j;
  const int vstride = dir ? -64 : 64;

  float r0, z0, n0, r1, z1, n1, r2, z2, n2, r3, z3, n3;
  int gidx = gstart;
  auto giload = [&](float& gr, float& gz, float& gn) {
    const float* p = gic + gidx;
    gr = p[j];
    gz = p[32 + j];
    gn = p[64 + j];
    gidx += gstride;
  };
  giload(r0, z0, n0);
  giload(r1, z1, n1);
  giload(r2, z2, n2);
  giload(r3, z3, n3);

  auto step = [&](bool pf, float& gr, float& gz, float& gn) {
    const float gir = gr, giz = gz, gin = gn;
    if (pf) giload(gr, gz, gn);  // global prefetch (vmcnt queue)
    hbuf[l] = h;  // same-wave LDS is in-order (proven rounds 4-12)
    f32x2 hv[16];
#pragma unroll
    for (int t = 0; t < 4; ++t) {
      const float4 hq = *(const float4*)&hbuf[hb + t * 8];
      const float4 hq2 = *(const float4*)&hbuf[hb + t * 8 + 4];
      hv[t * 4 + 0] = f32x2{hq.x, hq.y};
      hv[t * 4 + 1] = f32x2{hq.z, hq.w};
      hv[t * 4 + 2] = f32x2{hq2.x, hq2.y};
      hv[t * 4 + 3] = f32x2{hq2.z, hq2.w};
    }
    f32x2 sr2 = {0.f, 0.f}, sz2 = {0.f, 0.f}, sn2 = {0.f, 0.f};
    f32x2 sr3 = {0.f, 0.f}, sz3 = {0.f, 0.f}, sn3 = {0.f, 0.f};
#pragma unroll
    for (int t = 0; t < 8; ++t) {
      sr2 = __builtin_elementwise_fma(wr[t], hv[t], sr2);
      sz2 = __builtin_elementwise_fma(wz[t], hv[t], sz2);
      sn2 = __builtin_elementwise_fma(wn[t], hv[t], sn2);
      sr3 = __builtin_elementwise_fma(wr[8 + t], hv[8 + t], sr3);
      sz3 = __builtin_elementwise_fma(wz[8 + t], hv[8 + t], sz3);
      sn3 = __builtin_elementwise_fma(wn[8 + t], hv[8 + t], sn3);
    }
    const float sr = (sr2.x + sr2.y) + (sr3.x + sr3.y);
    const float sz = (sz2.x + sz2.y) + (sz3.x + sz3.y);
    const float sn = (sn2.x + sn2.y) + (sn3.x + sn3.y);
    // activations in base-2 (inputs pre-scaled): sigmoid(x)=rcp(1+2^-X)
    const float rg =
        __builtin_amdgcn_rcpf(1.0f + __builtin_amdgcn_exp2f(-(gir + sr)));
    const float ug =
        __builtin_amdgcn_rcpf(1.0f + __builtin_amdgcn_exp2f(-(giz + sz)));
    // tanh(a) = 1 - 2*rcp(2^A + 1), A = 2*log2e*a (n-side all pre-scaled)
    const float ng =
        1.0f - 2.0f * __builtin_amdgcn_rcpf(
                          __builtin_amdgcn_exp2f(gin + rg * (sn + bhn)) + 1.0f);
    h = ng + ug * (h - ng);
    *vp = h;
    vp += vstride;
  };
  for (int s = 0; s < NK; s += 4) {
    step(s + 4 < NK, r0, z0, n0);
    step(s + 5 < NK, r1, z1, n1);
    step(s + 6 < NK, r2, z2, n2);
    step(s + 7 < NK, r3, z3, n3);
  }
}

// R=8 attention v2 (round-12, PASSED): 4 waves/block share 64 rows, each
// covers a 128-key quarter; LDS combine; per-group stagger + skewed kt.
__global__ __launch_bounds__(256) void attn_core_kernel(
    const float* __restrict__ tsteps, const float* __restrict__ ktab,
    const float* __restrict__ val,
    const float* __restrict__ Wq, const float* __restrict__ bq,
    float* __restrict__ att) {
  __shared__ __align__(16) float kts[NK * NE + 64];  // skewed, 33 KB
  __shared__ __align__(16) float cbuf[4][64][16];    // 16 KB combine buffer
  __shared__ float lbuf[4][64];                      // 1 KB lsum partials
  __shared__ float wqs[NE * NE];
  __shared__ float bqs[NE];
  const int tid = threadIdx.x;
  for (int i = tid; i < NK * NE; i += 256) {
    const int k = i >> 4, e = i & 15;
    kts[(k << 4) + (((k >> 3) & 7) << 2) + e] = ktab[i];
  }
  for (int i = tid; i < NE * NE; i += 256) wqs[i] = Wq[i];
  if (tid < NE) bqs[tid] = bq[tid];
  __syncthreads();

  const int lane = tid & 63;
  const int g = lane >> 3;      // group 0..7
  const int r8 = lane & 7;      // row-in-group for scoring; d-eighth for acc
  const int wave = tid >> 6;    // k-quarter owner
  const int rowbase = blockIdx.x * 64 + g * 8;
  const int myrow = rowbase + r8;
  const int b = myrow >> 11;    // uniform per block (64-row span, 64|2048)

  const float pos = tsteps[myrow];
  const float divs[8] = {1.0f, 0.74989421f, 0.56234133f, 0.42169650f,
                         0.31622777f, 0.23713737f, 0.17782794f, 0.13335214f};
  float emb[NE];
#pragma unroll
  for (int m = 0; m < 8; ++m) {
    float a = 48.0f * pos * divs[m];
    emb[2 * m] = sinf(a);
    emb[2 * m + 1] = cosf(a);
  }
  float q[NE];
#pragma unroll
  for (int e = 0; e < NE; ++e) {
    float acc = bqs[e];
#pragma unroll
    for (int i = 0; i < NE; ++i) acc += emb[i] * wqs[e * NE + i];
    q[e] = acc * 0.25f;  // fold 1/sqrt(E)
  }
  const int lb = lane & ~7;  // group's lane 0
  const float* __restrict__ vb = val + (size_t)b * NK * 64;

  float acc[8][8];
#pragma unroll
  for (int m = 0; m < 8; ++m)
#pragma unroll
    for (int d = 0; d < 8; ++d) acc[m][d] = 0.f;
  float lsum = 0.f;

#pragma unroll
  for (int kb = 0; kb < 2; ++kb) {
    const int khi = (wave << 1) | kb;   // this wave's k-block (uniform)
#pragma unroll 2
    for (int i = 0; i < 64; ++i) {
      const int ii = (i + g * 8) & 63;  // group stagger (uniform in group)
      const int k = (khi << 6) | ii;
      const float4* kr =
          (const float4*)&kts[(k << 4) + (((k >> 3) & 7) << 2)];
      const float4 k0 = kr[0], k1 = kr[1], k2 = kr[2], k3 = kr[3];
      float s;
      s  = q[0] * k0.x + q[1] * k0.y + q[2] * k0.z + q[3] * k0.w;
      s += q[4] * k1.x + q[5] * k1.y + q[6] * k1.z + q[7] * k1.w;
      s += q[8] * k2.x + q[9] * k2.y + q[10] * k2.z + q[11] * k2.w;
      s += q[12] * k3.x + q[13] * k3.y + q[14] * k3.z + q[15] * k3.w;
      const float p = __expf(s);  // scores O(1): no max-sub needed
      lsum += p;
      const float* vr = vb + (size_t)k * 64 + r8 * 8;
      const float4 va = *(const float4*)(vr);
      const float4 vb4 = *(const float4*)(vr + 4);
      float pm[8];
#pragma unroll
      for (int m = 0; m < 8; ++m) pm[m] = bperm(lb + m, p);
#pragma unroll
      for (int m = 0; m < 8; ++m) {
        acc[m][0] += pm[m] * va.x;  acc[m][1] += pm[m] * va.y;
        acc[m][2] += pm[m] * va.z;  acc[m][3] += pm[m] * va.w;
        acc[m][4] += pm[m] * vb4.x; acc[m][5] += pm[m] * vb4.y;
        acc[m][6] += pm[m] * vb4.z; acc[m][7] += pm[m] * vb4.w;
      }
    }
  }

  // cross-wave combine: 4 partials per (row, dim); lsum totals once.
  lbuf[wave][lane] = lsum;
  float lt = 0.f;
  float* ob = att + (size_t)rowbase * 64 + r8 * 8;
#pragma unroll
  for (int mm = 0; mm < 8; mm += 2) {
    *(float4*)&cbuf[wave][lane][0] =
        make_float4(acc[mm][0], acc[mm][1], acc[mm][2], acc[mm][3]);
    *(float4*)&cbuf[wave][lane][4] =
        make_float4(acc[mm][4], acc[mm][5], acc[mm][6], acc[mm][7]);
    *(float4*)&cbuf[wave][lane][8] =
        make_float4(acc[mm + 1][0], acc[mm + 1][1], acc[mm + 1][2],
                    acc[mm + 1][3]);
    *(float4*)&cbuf[wave][lane][12] =
        make_float4(acc[mm + 1][4], acc[mm + 1][5], acc[mm + 1][6],
                    acc[mm + 1][7]);
    __syncthreads();
    if (mm == 0)
      lt = lbuf[0][lane] + lbuf[1][lane] + lbuf[2][lane] + lbuf[3][lane];
    if (wave == 0) {
      float s[16];
#pragma unroll
      for (int d4 = 0; d4 < 4; ++d4) {
        const float4 c0 = *(const float4*)&cbuf[0][lane][d4 * 4];
        const float4 c1 = *(const float4*)&cbuf[1][lane][d4 * 4];
        const float4 c2 = *(const float4*)&cbuf[2][lane][d4 * 4];
        const float4 c3 = *(const float4*)&cbuf[3][lane][d4 * 4];
        s[d4 * 4 + 0] = c0.x + c1.x + c2.x + c3.x;
        s[d4 * 4 + 1] = c0.y + c1.y + c2.y + c3.y;
        s[d4 * 4 + 2] = c0.z + c1.z + c2.z + c3.z;
        s[d4 * 4 + 3] = c0.w + c1.w + c2.w + c3.w;
      }
      const float im0 = 1.0f / bperm(lb + mm, lt);
      const float im1 = 1.0f / bperm(lb + mm + 1, lt);
      *(float4*)(ob + mm * 64) =
          make_float4(s[0] * im0, s[1] * im0, s[2] * im0, s[3] * im0);
      *(float4*)(ob + mm * 64 + 4) =
          make_float4(s[4] * im0, s[5] * im0, s[6] * im0, s[7] * im0);
      *(float4*)(ob + (mm + 1) * 64) =
          make_float4(s[8] * im1, s[9] * im1, s[10] * im1, s[11] * im1);
      *(float4*)(ob + (mm + 1) * 64 + 4) =
          make_float4(s[12] * im1, s[13] * im1, s[14] * im1, s[15] * im1);
    }
    __syncthreads();
  }
}

// Per-row MLP on folded weights: out = W2 @ relu(W1' @ ar + b1') + b2.
__global__ __launch_bounds__(256) void mlp_kernel(
    const float* __restrict__ att,
    const float* __restrict__ w1p, const float* __restrict__ b1p,
    const float* __restrict__ W2, const float* __restrict__ b2,
    float* __restrict__ out) {
  __shared__ __align__(16) float w1s[NHID * 64];   // 12.8 KB
  __shared__ __align__(16) float w2s[NO * NHID];   // 8.2 KB
  __shared__ float b1s[NHID], b2s[NO];
  const int tid = threadIdx.x;
  for (int i = tid; i < NHID * 64; i += 256) w1s[i] = w1p[i];
  for (int i = tid; i < NO * NHID; i += 256) w2s[i] = W2[i];
  if (tid < NHID) b1s[tid] = b1p[tid];
  if (tid < NO) b2s[tid] = b2[tid];
  __syncthreads();

  const int row = blockIdx.x * 256 + tid;
  float ar[64];
  const float4* a4 = (const float4*)(att + (size_t)row * 64);
#pragma unroll
  for (int d4 = 0; d4 < 16; ++d4) {
    float4 v = a4[d4];
    ar[d4 * 4 + 0] = v.x;
    ar[d4 * 4 + 1] = v.y;
    ar[d4 * 4 + 2] = v.z;
    ar[d4 * 4 + 3] = v.w;
  }
  float outv[NO];
#pragma unroll
  for (int oo = 0; oo < NO; ++oo) outv[oo] = b2s[oo];
#pragma unroll 2
  for (int o = 0; o < NHID; ++o) {
    float acc = b1s[o];
    const float4* w4 = (const float4*)&w1s[o * 64];
#pragma unroll
    for (int i4 = 0; i4 < 16; ++i4) {
      float4 ww = w4[i4];
      acc += ar[i4 * 4 + 0] * ww.x + ar[i4 * 4 + 1] * ww.y +
             ar[i4 * 4 + 2] * ww.z + ar[i4 * 4 + 3] * ww.w;
    }
    const float hv = fmaxf(acc, 0.f);
#pragma unroll
    for (int oo = 0; oo < NO; ++oo) outv[oo] += hv * w2s[oo * NHID + o];
  }
  float* orow = out + (size_t)row * NO;
#pragma unroll
  for (int oo = 0; oo < NO; ++oo) orow[oo] = outv[oo];
}

extern "C" void kernel_launch(void* const* d_in, const int* in_sizes, int n_in,
                              void* d_out, int out_size, void* d_ws, size_t ws_size,
                              hipStream_t stream) {
  const float* z = (const float*)d_in[0];
  const float* ts = (const float*)d_in[1];
  const float* refq = (const float*)d_in[2];
  const float* Wih_f = (const float*)d_in[3];
  const float* Whh_f = (const float*)d_in[4];
  const float* bih_f = (const float*)d_in[5];
  const float* bhh_f = (const float*)d_in[6];
  const float* Wih_b = (const float*)d_in[7];
  const float* Whh_b = (const float*)d_in[8];
  const float* bih_b = (const float*)d_in[9];
  const float* bhh_b = (const float*)d_in[10];
  const float* Wq = (const float*)d_in[11];
  const float* bq = (const float*)d_in[12];
  const float* Wk = (const float*)d_in[13];
  const float* bk = (const float*)d_in[14];
  const float* Wv = (const float*)d_in[15];
  const float* bv = (const float*)d_in[16];
  const float* W1 = (const float*)d_in[17];
  const float* b1 = (const float*)d_in[18];
  const float* W2 = (const float*)d_in[19];
  const float* b2 = (const float*)d_in[20];

  float* ws = (float*)d_ws;
  float* gi = ws;               // 3,145,728 (overlaid with att)
  float* att = ws;              // 4,194,304
  float* val = ws + 4194304;    // 1,048,576
  float* ktab = ws + 5242880;   // 8,192
  float* w1p = ws + 5251072;    // 3,200
  float* b1p = ws + 5254272;    // 64
  float* out = (float*)d_out;

  prep_kernel<<<3, 256, 0, stream>>>(refq, Wk, bk, Wv, bv, W1, b1,
                                     ktab, w1p, b1p);
  prep_gi_kernel<<<128, 256, 0, stream>>>(z, Wih_f, bih_f, bhh_f,
                                          Wih_b, bih_b, bhh_b, gi);
  gru_kernel<<<32, 64, 0, stream>>>(gi, Whh_f, bhh_f, Whh_b, bhh_b, val);
  attn_core_kernel<<<1024, 256, 0, stream>>>(ts, ktab, val, Wq, bq, att);
  mlp_kernel<<<256, 256, 0, stream>>>(att, w1p, b1p, W2, b2, out);
}